// Round 7
// baseline (275.795 us; speedup 1.0000x reference)
//
#include <hip/hip_runtime.h>

#define IN_F   4096
#define OUT_F  11008
#define BATCH  16
#define BLOCK  256
#define SPLITK 8
#define KCHUNK (IN_F / SPLITK)   // 512 k per block
#define NITER  (KCHUNK / 64)     // 8 iterations, 64 k each (2 mfma k-steps)

typedef short s16x8 __attribute__((ext_vector_type(8)));   // bf16x8 frag
typedef float f32x4 __attribute__((ext_vector_type(4)));
typedef int   i32x4 __attribute__((ext_vector_type(4)));
typedef unsigned short u16;

__device__ __forceinline__ u16 f32_to_bf16_rne(float f) {
    unsigned u = __float_as_uint(f);
    unsigned r = u + 0x7FFFu + ((u >> 16) & 1u);
    return (u16)(r >> 16);
}
__device__ __forceinline__ float bf16_bits_to_f32(u16 h) {
    return __uint_as_float((unsigned)h << 16);
}
__device__ __forceinline__ short bf16_trunc(float f) {   // exact for |f|<=127 ints
    return (short)(u16)(__float_as_uint(f) >> 16);
}

// One dispatch, three jobs (all contiguous streaming):
//  blocks [0, 11008):        pack w row bid: int32 -> int8 bytes into wp
//  blocks [11008, +256):     x f32 -> bf16 hi/lo planes (RNE split)
//  blocks [11264, +688):     out[b][o] = bias[o]
__global__ __launch_bounds__(BLOCK) void prep_kernel(
    const float* __restrict__ x, const int* __restrict__ w,
    const float* __restrict__ bias, float* __restrict__ out,
    unsigned char* __restrict__ wp, u16* __restrict__ xhi, u16* __restrict__ xlo)
{
    const int bid = blockIdx.x;
    const int tid = threadIdx.x;
    if (bid < OUT_F) {
        // one weight row: 4096 int32 = 1024 i32x4; 4 per thread, wave-contiguous
        const i32x4* __restrict__ src = (const i32x4*)(w + (size_t)bid * IN_F);
        unsigned* __restrict__ dst = (unsigned*)(wp + (size_t)bid * IN_F);
        #pragma unroll
        for (int j = 0; j < 4; ++j) {
            int g = tid + j * BLOCK;                 // i32x4 group index
            i32x4 v = __builtin_nontemporal_load(src + g);
            unsigned p = (unsigned)(v[0] & 0xFF)
                       | ((unsigned)(v[1] & 0xFF) << 8)
                       | ((unsigned)(v[2] & 0xFF) << 16)
                       | ((unsigned)(v[3] & 0xFF) << 24);
            dst[g] = p;                              // 4 packed int8
        }
    } else if (bid < OUT_F + (BATCH * IN_F) / BLOCK) {
        int i = (bid - OUT_F) * BLOCK + tid;         // < 65536
        float v  = x[i];
        u16 h    = f32_to_bf16_rne(v);
        u16 l    = f32_to_bf16_rne(v - bf16_bits_to_f32(h));
        xhi[i] = h;
        xlo[i] = l;
    } else {
        int i = (bid - OUT_F - (BATCH * IN_F) / BLOCK) * BLOCK + tid;  // < 176128
        out[i] = bias[i % OUT_F];
    }
}

// Streaming MFMA over packed int8 weights. Block (bx,by): 64 outputs, 512 k.
// Wave wv: 16 outputs o0 = bx*64+wv*16. Per iteration t (64 k):
//   lane(n,quad) weight bytes  wp[o0+n][kb + t*64 + quad*16 .. +16)   (one 16B load)
//   x frags at the SAME permuted k offsets -> dot product unchanged.
// 4 MFMAs per iter: (xhi,xlo planes) x (lo,hi byte halves). All 8 weight
// loads issued up-front (8 outstanding HBM reads per wave).
__global__ __launch_bounds__(BLOCK) void qlin_kernel(
    const unsigned char* __restrict__ wp,   // [11008][4096] int8
    const float* __restrict__ scale,
    const u16* __restrict__ xhi,            // [16][4096] bf16 bits
    const u16* __restrict__ xlo,
    float* __restrict__ out)                // [16,11008], pre-filled with bias
{
    const int tid  = threadIdx.x;
    const int lane = tid & 63;
    const int wv   = tid >> 6;
    const int n    = lane & 15;
    const int quad = lane >> 4;
    const int o0   = blockIdx.x * 64 + wv * 16;
    const int kb   = blockIdx.y * KCHUNK;

    const i32x4* __restrict__ wrow =
        (const i32x4*)(wp + (size_t)(o0 + n) * IN_F + kb + quad * 16);

    i32x4 wq[NITER];
    #pragma unroll
    for (int t = 0; t < NITER; ++t)
        wq[t] = __builtin_nontemporal_load(wrow + t * 4);   // +t*64 bytes

    const u16* __restrict__ xh = xhi + n * IN_F + kb + quad * 16;
    const u16* __restrict__ xl = xlo + n * IN_F + kb + quad * 16;

    f32x4 acc = {0.f, 0.f, 0.f, 0.f};

    #pragma unroll
    for (int t = 0; t < NITER; ++t) {
        s16x8 ahlo = *(const s16x8*)(xh + t * 64);
        s16x8 ahhi = *(const s16x8*)(xh + t * 64 + 8);
        s16x8 allo = *(const s16x8*)(xl + t * 64);
        s16x8 alhi = *(const s16x8*)(xl + t * 64 + 8);

        s16x8 blo, bhi;
        #pragma unroll
        for (int e = 0; e < 2; ++e) {
            int v1 = wq[t][e];       // bytes e*4 .. e*4+3   (lo half: k 0..7)
            int v2 = wq[t][2 + e];   // bytes 8+e*4 ..       (hi half: k 8..15)
            #pragma unroll
            for (int b = 0; b < 4; ++b) {
                blo[e * 4 + b] = bf16_trunc((float)((v1 << (24 - 8 * b)) >> 24));
                bhi[e * 4 + b] = bf16_trunc((float)((v2 << (24 - 8 * b)) >> 24));
            }
        }

        acc = __builtin_amdgcn_mfma_f32_16x16x32_bf16(ahlo, blo, acc, 0, 0, 0);
        acc = __builtin_amdgcn_mfma_f32_16x16x32_bf16(allo, blo, acc, 0, 0, 0);
        acc = __builtin_amdgcn_mfma_f32_16x16x32_bf16(ahhi, bhi, acc, 0, 0, 0);
        acc = __builtin_amdgcn_mfma_f32_16x16x32_bf16(alhi, bhi, acc, 0, 0, 0);
    }

    const int   o  = o0 + n;
    const float sc = scale[o];
    #pragma unroll
    for (int r = 0; r < 4; ++r) {
        const int b = quad * 4 + r;   // D row = batch
        atomicAdd(&out[(size_t)b * OUT_F + o], acc[r] * sc);
    }
}

extern "C" void kernel_launch(void* const* d_in, const int* in_sizes, int n_in,
                              void* d_out, int out_size, void* d_ws, size_t ws_size,
                              hipStream_t stream) {
    const float* x     = (const float*)d_in[0];
    const int*   w     = (const int*)d_in[1];
    const float* scale = (const float*)d_in[2];
    const float* bias  = (const float*)d_in[3];
    float* out = (float*)d_out;

    unsigned char* wp = (unsigned char*)d_ws;                 // 45.1 MB
    u16* xhi = (u16*)(wp + (size_t)OUT_F * IN_F);             // +128 KB
    u16* xlo = xhi + BATCH * IN_F;                            // +128 KB

    const int PREP_BLOCKS = OUT_F + (BATCH * IN_F) / BLOCK + (BATCH * OUT_F) / BLOCK;
    prep_kernel<<<PREP_BLOCKS, BLOCK, 0, stream>>>(x, w, bias, out, wp, xhi, xlo);

    dim3 grid(OUT_F / 64, SPLITK);   // 172 x 8 = 1376 blocks
    qlin_kernel<<<grid, dim3(BLOCK), 0, stream>>>(wp, scale, xhi, xlo, out);
}

// Round 8
// 260.677 us; speedup vs baseline: 1.0580x; 1.0580x over previous
//
#include <hip/hip_runtime.h>

#define IN_F   4096
#define OUT_F  11008
#define BATCH  16
#define BLOCK  256
#define SPLITK 16
#define KCHUNK (IN_F / SPLITK)   // 256 k per block
#define NSTEP  (KCHUNK / 32)     // 8 mfma k-steps (16x16x32)

typedef short s16x8 __attribute__((ext_vector_type(8)));   // bf16x8 frag
typedef float f32x4 __attribute__((ext_vector_type(4)));
typedef int   i32x4 __attribute__((ext_vector_type(4)));
typedef unsigned short u16;

__device__ __forceinline__ u16 f32_to_bf16_rne(float f) {
    unsigned u = __float_as_uint(f);
    unsigned r = u + 0x7FFFu + ((u >> 16) & 1u);
    return (u16)(r >> 16);
}
__device__ __forceinline__ float bf16_bits_to_f32(u16 h) {
    return __uint_as_float((unsigned)h << 16);
}
__device__ __forceinline__ short bf16_trunc(float f) {   // exact for |f|<=127 ints
    return (short)(u16)(__float_as_uint(f) >> 16);
}

// One dispatch, two jobs:
//  blocks [0, 256):    x[16][4096] f32 -> bf16 hi/lo planes in ws (RNE split)
//  blocks [256, 944):  out[b][o] = bias[o]  (so main kernel can atomicAdd)
__global__ __launch_bounds__(BLOCK) void prep_kernel(
    const float* __restrict__ x, const float* __restrict__ bias,
    float* __restrict__ out, u16* __restrict__ xhi, u16* __restrict__ xlo)
{
    const int bid = blockIdx.x;
    const int tid = threadIdx.x;
    if (bid < (BATCH * IN_F) / BLOCK) {
        int i = bid * BLOCK + tid;
        float v  = x[i];
        u16 h    = f32_to_bf16_rne(v);
        u16 l    = f32_to_bf16_rne(v - bf16_bits_to_f32(h));
        xhi[i] = h;
        xlo[i] = l;
    } else {
        int i = (bid - (BATCH * IN_F) / BLOCK) * BLOCK + tid;  // < 176128
        out[i] = bias[i % OUT_F];
    }
}

// Streaming MFMA, zero LDS/barriers, DEEP read pipeline:
// each wave issues ALL 16 weight dwordx4 loads for its K-chunk back-to-back
// (16 KB/wave outstanding) before consuming them in issue order.
// Block (bx,by): 64 outputs [bx*64..), K-chunk [by*256..). Wave wv owns
// o0 = bx*64 + wv*16. mfma_f32_16x16x32_bf16 per step (x2 hi/lo):
//   A[m=lane&15][k=quad*8+j]  <- x bf16 planes (L2-hot, 256 KB)
//   B[k=quad*8+j][n=lane&15]  <- w row o0+n (int8-in-int32 -> bf16, exact)
//   D[row=quad*4+r][col=n]    -> atomicAdd scale[o]*acc into bias-filled out
__global__ __launch_bounds__(BLOCK) void qlin_kernel(
    const int*   __restrict__ w,      // [11008, 4096] int8 in int32
    const float* __restrict__ scale,  // [11008]
    const u16*   __restrict__ xhi,    // [16, 4096] bf16 bits
    const u16*   __restrict__ xlo,
    float* __restrict__ out)          // [16, 11008], pre-filled with bias
{
    const int tid  = threadIdx.x;
    const int lane = tid & 63;
    const int wv   = tid >> 6;
    const int n    = lane & 15;
    const int quad = lane >> 4;
    const int o0   = blockIdx.x * 64 + wv * 16;
    const int kb   = blockIdx.y * KCHUNK;

    // ---- issue ALL weight loads up-front: 16 x dwordx4 per lane ----
    const i32x4* __restrict__ wbase =
        (const i32x4*)(w + (size_t)(o0 + n) * IN_F + kb);
    const int qb = quad * 2;          // i32x4 offset of this quad's 8 k

    i32x4 wq[2 * NSTEP];
    #pragma unroll
    for (int s = 0; s < NSTEP; ++s) {
        wq[2 * s]     = wbase[s * 8 + qb];       // k j=0..3
        wq[2 * s + 1] = wbase[s * 8 + qb + 1];   // k j=4..7
    }

    const u16* __restrict__ xh = xhi + n * IN_F + kb + quad * 8;
    const u16* __restrict__ xl = xlo + n * IN_F + kb + quad * 8;

    f32x4 acc = {0.f, 0.f, 0.f, 0.f};

    s16x8 ah = *(const s16x8*)xh;
    s16x8 al = *(const s16x8*)xl;

    #pragma unroll
    for (int s = 0; s < NSTEP; ++s) {
        s16x8 ah2, al2;
        if (s + 1 < NSTEP) {
            ah2 = *(const s16x8*)(xh + (s + 1) * 32);
            al2 = *(const s16x8*)(xl + (s + 1) * 32);
        }

        // int32 -> f32 -> bf16 truncate: exact for |v| <= 127
        s16x8 bfrag;
        #pragma unroll
        for (int e = 0; e < 4; ++e) {
            bfrag[e]     = bf16_trunc((float)wq[2 * s][e]);
            bfrag[4 + e] = bf16_trunc((float)wq[2 * s + 1][e]);
        }

        acc = __builtin_amdgcn_mfma_f32_16x16x32_bf16(ah, bfrag, acc, 0, 0, 0);
        acc = __builtin_amdgcn_mfma_f32_16x16x32_bf16(al, bfrag, acc, 0, 0, 0);

        ah = ah2;
        al = al2;
    }

    const int   o  = o0 + n;
    const float sc = scale[o];
    #pragma unroll
    for (int r = 0; r < 4; ++r) {
        const int b = quad * 4 + r;   // D row = batch
        atomicAdd(&out[(size_t)b * OUT_F + o], acc[r] * sc);
    }
}

extern "C" void kernel_launch(void* const* d_in, const int* in_sizes, int n_in,
                              void* d_out, int out_size, void* d_ws, size_t ws_size,
                              hipStream_t stream) {
    const float* x     = (const float*)d_in[0];
    const int*   w     = (const int*)d_in[1];
    const float* scale = (const float*)d_in[2];
    const float* bias  = (const float*)d_in[3];
    float* out = (float*)d_out;

    u16* xhi = (u16*)d_ws;                                       // 128 KB
    u16* xlo = xhi + BATCH * IN_F;                               // +128 KB

    const int PREP_BLOCKS = (BATCH * IN_F) / BLOCK + (BATCH * OUT_F) / BLOCK;
    prep_kernel<<<PREP_BLOCKS, BLOCK, 0, stream>>>(x, bias, out, xhi, xlo);

    dim3 grid(OUT_F / 64, SPLITK);   // 172 x 16 = 2752 blocks
    qlin_kernel<<<grid, dim3(BLOCK), 0, stream>>>(w, scale, xhi, xlo, out);
}